// Round 6
// baseline (488.420 us; speedup 1.0000x reference)
//
#include <hip/hip_runtime.h>
#include <hip/hip_bf16.h>

typedef __attribute__((ext_vector_type(8))) short bf16x8;
typedef __attribute__((ext_vector_type(4))) float f32x4;

#define MFMA16(a, b, c) __builtin_amdgcn_mfma_f32_16x16x32_bf16((a), (b), (c), 0, 0, 0)

#define N_ 64
#define C_ 192
#define T_ 128
#define V_ 25
#define S_ 3
#define MID 64
#define TV 3200          // T_*V_
#define C3 576           // 3*C_
#define OUT_ELEMS 39321600ULL
#define NCHUNK 16        // T-chunks for k2 partials
#define PSTRIDE 640      // padded 25*25 partial stride (floats)

static __device__ __forceinline__ float bf2f(ushort u) {
    union { unsigned int i; float f; } x; x.i = ((unsigned int)u) << 16; return x.f;
}
static __device__ __forceinline__ ushort f2bf(float f) {
    union { float f; unsigned int i; } x; x.f = f;
    unsigned int r = x.i + 0x7fffu + ((x.i >> 16) & 1u);
    return (ushort)(r >> 16);
}
// HW packed f32->bf16 (v_cvt_pk_bf16_f32, RNE — bit-identical to f2bf on normals)
static __device__ __forceinline__ unsigned int packcvt(float a, float b) {
    __hip_bfloat162 h = __float22bfloat162_rn(make_float2(a, b));
    union { __hip_bfloat162 h; unsigned int u; } c; c.h = h; return c.u;
}

// ---------------------------------------------------------------------------
// kconv: fp32 -> bf16 row-major copy (weights). n4 = number of float4 chunks.
// ---------------------------------------------------------------------------
__global__ __launch_bounds__(256) void kconv(const float* __restrict__ src,
                                             ushort* __restrict__ dst, int n4) {
    int i = blockIdx.x * 256 + threadIdx.x;
    if (i < n4) {
        float4 d = *(const float4*)(src + (size_t)i * 4);
        unsigned int* o = (unsigned int*)dst + (size_t)i * 2;
        o[0] = packcvt(d.x, d.y);
        o[1] = packcvt(d.z, d.w);
    }
}

// ---------------------------------------------------------------------------
// K1: qkvT[n][m][o] = sum_k x[n][k][m] * Wqkv[o][k] + bqkv[o]   (bf16 out)
// 512-thread blocks, two 64-row m-tiles. A-fragments hoisted to registers;
// the dead As LDS (51KB) is reused as the SECOND B buffer -> double-buffered
// B with ONE barrier per o-tile: issue W(oi+1) loads -> MFMA(oi) hides the
// L2 latency -> ds_write W(oi+1) -> barrier. No LDS growth, staging regs
// live only inside the loop body (no R3 spill pattern).
// ---------------------------------------------------------------------------
__global__ __launch_bounds__(512, 4) void k1_qkv(const float* __restrict__ x,
                                                 const ushort* __restrict__ Wbf,
                                                 const float* __restrict__ bias,
                                                 ushort* __restrict__ qkvT) {
    int m0 = blockIdx.x * 128, n = blockIdx.y;
    __shared__ __align__(16) ushort As[2][64 * 200]; // [half][m][c]; dead after afrag
    __shared__ __align__(16) ushort Bs[64 * 200];    // B buffer 0; front aliased scratch
    __shared__ float biasS[C3];
    unsigned int* scratchU = (unsigned int*)Bs;   // 96 rows x 35 dwords (odd stride)
    ushort* scratchS = Bs;                        // same, short view: row stride 70
    ushort* BsAlt = (ushort*)As;                  // B buffer 1 (reuses dead As[0])
    int tid = threadIdx.x;

    for (int i = tid; i < C3; i += 512) biasS[i] = bias[i];

    // ---- stage A: 2 halves x 2 groups of 96 channels (fused f32->bf16 transpose)
    for (int h = 0; h < 2; h++) {
        for (int cg = 0; cg < 2; cg++) {
            if (h || cg) __syncthreads();  // transpose reads of scratch done
#pragma unroll
            for (int j = 0; j < 3; j++) {
                int chunk = tid + j * 512;          // 1536 = 96c * 16 f4
                int cc = chunk >> 4, m4 = chunk & 15;
                float4 d = *(const float4*)(x + ((size_t)n * C_ + cg * 96 + cc) * TV
                                            + m0 + h * 64 + m4 * 4);
                scratchU[cc * 35 + m4 * 2]     = packcvt(d.x, d.y);
                scratchU[cc * 35 + m4 * 2 + 1] = packcvt(d.z, d.w);
            }
            __syncthreads();
#pragma unroll
            for (int j = 0; j < 12; j++) {
                int idx = tid + j * 512;            // 6144 = 64m * 96c
                int mm = idx / 96, cc = idx % 96;
                As[h][mm * 200 + cg * 96 + cc] = scratchS[cc * 70 + mm];
            }
        }
    }
    __syncthreads();   // As complete, scratch dead -> safe to read frags / write Bs

    int wave = tid >> 6, lane = tid & 63;
    int h = wave >> 2, w4 = wave & 3;
    int mb = (w4 >> 1) * 32, ob = (w4 & 1) * 32;
    int lrow = lane & 15, lk = lane >> 4;
    const ushort* myAs = As[h];
    int mglob = m0 + h * 64;

    // ---- hoist A-fragments to registers: 12 x bf16x8 = 48 VGPR, read ONCE
    bf16x8 afrag[2][6];
#pragma unroll
    for (int ks = 0; ks < 6; ks++)
#pragma unroll
        for (int mt = 0; mt < 2; mt++)
            afrag[mt][ks] = *(const bf16x8*)&myAs[(mb + mt * 16 + lrow) * 200 + ks * 32 + lk * 8];

    // per-thread W staging geometry (6 small ints, o-loop scope only)
    int sr[3], sc[3];
#pragma unroll
    for (int j = 0; j < 3; j++) {
        int chunk = tid + j * 512;          // 1536 = 64 rows * 24 uint4
        sr[j] = chunk / 24; sc[j] = (chunk % 24) * 8;
    }

    // ---- prologue: tile 0 -> B0 (Bs)
    {
        uint4 st[3];
#pragma unroll
        for (int j = 0; j < 3; j++)
            st[j] = *(const uint4*)(Wbf + (size_t)sr[j] * C_ + sc[j]);
#pragma unroll
        for (int j = 0; j < 3; j++)
            *(uint4*)&Bs[sr[j] * 200 + sc[j]] = st[j];
    }
    __syncthreads();   // B0 visible; afrag reads retired -> As reusable

    // ---- loop over 9 o-tiles, double-buffered B, ONE barrier per tile ----
    for (int oi = 0; oi < 9; oi++) {
        int o0 = oi * 64;
        const ushort* Bcur = (oi & 1) ? BsAlt : Bs;
        ushort* Bnxt = (oi & 1) ? Bs : BsAlt;

        // issue next tile's W loads (latency hides under MFMA below)
        uint4 st[3];
        if (oi < 8) {
#pragma unroll
            for (int j = 0; j < 3; j++)
                st[j] = *(const uint4*)(Wbf + (size_t)(o0 + 64 + sr[j]) * C_ + sc[j]);
        }

        f32x4 acc[2][2];
#pragma unroll
        for (int i = 0; i < 2; i++)
#pragma unroll
            for (int j = 0; j < 2; j++) acc[i][j] = (f32x4){0.f, 0.f, 0.f, 0.f};

#pragma unroll
        for (int ks = 0; ks < 6; ks++) {
            bf16x8 b[2];
#pragma unroll
            for (int ot = 0; ot < 2; ot++)
                b[ot] = *(const bf16x8*)&Bcur[(ob + ot * 16 + lrow) * 200 + ks * 32 + lk * 8];
#pragma unroll
            for (int mt = 0; mt < 2; mt++)
#pragma unroll
                for (int ot = 0; ot < 2; ot++)
                    acc[mt][ot] = MFMA16(afrag[mt][ks], b[ot], acc[mt][ot]);
        }

        // write next tile into the other buffer (loads have returned by now)
        if (oi < 8) {
#pragma unroll
            for (int j = 0; j < 3; j++)
                *(uint4*)&Bnxt[sr[j] * 200 + sc[j]] = st[j];
        }

        ushort* op = qkvT + ((size_t)n * TV + mglob) * C3 + o0;
#pragma unroll
        for (int mt = 0; mt < 2; mt++) {
#pragma unroll
            for (int ot = 0; ot < 2; ot++) {
                int o = ob + ot * 16 + lrow;
                float bv = biasS[o0 + o];
                ushort* col = op + o;
#pragma unroll
                for (int r = 0; r < 4; r += 2) {
                    int m = mb + mt * 16 + lk * 4 + r;
                    unsigned int pk = packcvt(acc[mt][ot][r] + bv, acc[mt][ot][r + 1] + bv);
                    col[(size_t)m * C3] = (ushort)(pk & 0xffffu);
                    col[(size_t)(m + 1) * C3] = (ushort)(pk >> 16);
                }
            }
        }
        __syncthreads();   // all reads of Bcur done + Bnxt visible
    }
}

// ---------------------------------------------------------------------------
// K2p: partial[((n*3+s)*16+tc)][u][v] = sum over 8 t's of q.k  (fp32)
// grid (16,3,64) = 3072 blocks; each wave handles 2 t's independently.
// ---------------------------------------------------------------------------
__global__ __launch_bounds__(256) void k2_att(const ushort* __restrict__ qkvT,
                                              float* __restrict__ partial) {
    int tc = blockIdx.x, s = blockIdx.y, n = blockIdx.z;
    __shared__ ushort tiles[4 * 2 * 32 * 72];   // [wave][q/k][32 rows][64+8]
    __shared__ float red[4 * 32 * 33];
    int tid = threadIdx.x, wave = tid >> 6, lane = tid & 63;
    ushort* myQ = &tiles[wave * 2 * 2304];
    ushort* myK = myQ + 2304;

    // zero pad rows 25..31 of both tiles (never written again)
    if (lane < 63) {
        *(uint4*)&myQ[1800 + lane * 8] = (uint4){0, 0, 0, 0};
        *(uint4*)&myK[1800 + lane * 8] = (uint4){0, 0, 0, 0};
    }

    const size_t nbase = (size_t)n * TV * C3;
    int qoff = s * MID;
    int koff = C_ + s * MID;
    int lrow = lane & 15, lk = lane >> 4;

    f32x4 acc[2][2];
#pragma unroll
    for (int i = 0; i < 2; i++)
#pragma unroll
        for (int j = 0; j < 2; j++) acc[i][j] = (f32x4){0.f, 0.f, 0.f, 0.f};

#pragma unroll
    for (int i = 0; i < 2; i++) {
        int t = tc * 8 + wave + 4 * i;
#pragma unroll
        for (int j = 0; j < 7; j++) {
            int idx = lane + j * 64;
            if (idx < 400) {
                int op = idx / 200, rr = idx % 200;
                int row = rr >> 3, c16 = rr & 7;
                int chan = (op ? koff : qoff) + c16 * 8;
                uint4 d = *(const uint4*)(qkvT + nbase + (size_t)(t * V_ + row) * C3 + chan);
                *(uint4*)((op ? myK : myQ) + row * 72 + c16 * 8) = d;
            }
        }
#pragma unroll
        for (int ks = 0; ks < 2; ks++) {
            bf16x8 a0 = *(const bf16x8*)&myQ[lrow * 72 + ks * 32 + lk * 8];
            bf16x8 a1 = *(const bf16x8*)&myQ[(16 + lrow) * 72 + ks * 32 + lk * 8];
            bf16x8 b0 = *(const bf16x8*)&myK[lrow * 72 + ks * 32 + lk * 8];
            bf16x8 b1 = *(const bf16x8*)&myK[(16 + lrow) * 72 + ks * 32 + lk * 8];
            acc[0][0] = MFMA16(a0, b0, acc[0][0]);
            acc[0][1] = MFMA16(a0, b1, acc[0][1]);
            acc[1][0] = MFMA16(a1, b0, acc[1][0]);
            acc[1][1] = MFMA16(a1, b1, acc[1][1]);
        }
    }

#pragma unroll
    for (int ub = 0; ub < 2; ub++)
#pragma unroll
        for (int vb = 0; vb < 2; vb++)
#pragma unroll
            for (int r = 0; r < 4; r++) {
                int u = ub * 16 + lk * 4 + r, v = vb * 16 + lrow;
                red[wave * 1056 + u * 33 + v] = acc[ub][vb][r];
            }
    __syncthreads();

    float* pb = partial + (((size_t)n * S_ + s) * NCHUNK + tc) * PSTRIDE;
    for (int idx = tid; idx < 1024; idx += 256) {
        int u = idx >> 5, v = idx & 31;
        if (u < V_ && v < V_) {
            float sum = red[u * 33 + v] + red[1056 + u * 33 + v] +
                        red[2112 + u * 33 + v] + red[3168 + u * 33 + v];
            pb[u * V_ + v] = sum;
        }
    }
}

// ---------------------------------------------------------------------------
// K2r: attOut[ns][r] = tanh(sum_j partial[ns][j][r] / 8192)
// ---------------------------------------------------------------------------
__global__ __launch_bounds__(256) void k2_reduce(const float* __restrict__ partial,
                                                 float* __restrict__ attOut) {
    int idx = blockIdx.x * 256 + threadIdx.x;
    if (idx >= 192 * 625) return;
    int ns = idx / 625, r = idx % 625;
    const float* p = partial + (size_t)ns * NCHUNK * PSTRIDE + r;
    float s = 0.f;
#pragma unroll
    for (int j = 0; j < NCHUNK; j++) s += p[j * PSTRIDE];
    attOut[(size_t)ns * 625 + r] = tanhf(s * (1.0f / 8192.0f));
}

// ---------------------------------------------------------------------------
// K3: yT[n][t*25+u][c'] = sum_v att[n][s(c')][u][v] * qkv_v[n][t*25+v][c']
// att address is wave-uniform (readfirstlane) -> compiler emits s_load from
// K$: no LDS, no staging, no sync. v-outer/u-inner with 25 independent
// accumulators -> fully pipelined v_fmac (no serial 25-deep chains).
// ---------------------------------------------------------------------------
__global__ __launch_bounds__(192) void k3_y(const ushort* __restrict__ qkvT,
                                            const float* __restrict__ attF,
                                            ushort* __restrict__ yT) {
    int t = blockIdx.x, n = blockIdx.y;
    int tid = threadIdx.x;
    int c = tid;
    int s = __builtin_amdgcn_readfirstlane(tid >> 6);   // wave-uniform subset id
    const float* __restrict__ as = attF + ((size_t)n * S_ + s) * 625;

    const ushort* vb = qkvT + ((size_t)n * TV + (size_t)t * V_) * C3 + 2 * C_ + c;
    float vreg[25];
#pragma unroll
    for (int v = 0; v < 25; v++) vreg[v] = bf2f(vb[(size_t)v * C3]);

    float acc[25];
#pragma unroll
    for (int u = 0; u < 25; u++) acc[u] = 0.f;

#pragma unroll
    for (int v = 0; v < 25; v++) {
        float av = vreg[v];
#pragma unroll
        for (int u = 0; u < 25; u++) acc[u] += as[u * 25 + v] * av;
    }

    ushort* yb = yT + ((size_t)n * TV + (size_t)t * V_) * C_ + c;
#pragma unroll
    for (int u = 0; u < 25; u++) yb[(size_t)u * C_] = f2bf(acc[u]);
}

// ---------------------------------------------------------------------------
// K4: out[n][o][m] = LeakyReLU(x + (yT.Wff^T)*inv[o] + shift[o], 0.1)  fp32
// m-tile 64, A staged once + A-fragments hoisted to registers (o-loop reads
// only B from LDS). BN constants hoisted out of the loop. zT aliases Bs ->
// LDS ~51.5KB, 3 blocks/CU (VGPR <=170 via launch_bounds(256,3)).
// (R5-verified version, unchanged.)
// ---------------------------------------------------------------------------
__global__ __launch_bounds__(256, 3) void k4_out(const ushort* __restrict__ yT,
                                                 const ushort* __restrict__ Wbf,
                                                 const float* __restrict__ bff,
                                                 const float* __restrict__ gamma,
                                                 const float* __restrict__ beta,
                                                 const float* __restrict__ rmean,
                                                 const float* __restrict__ rvar,
                                                 const float* __restrict__ x,
                                                 float* __restrict__ out) {
    int m0 = blockIdx.x * 64, n = blockIdx.y;
    __shared__ __align__(16) ushort As[64 * 200];
    __shared__ __align__(16) ushort Bs[64 * 200]; // 25.6KB; reused as fp32 zT[64][68]
    __shared__ float invS[C_], shiftS[C_];
    float* zT = (float*)Bs;
    int tid = threadIdx.x;

    const ushort* ab = yT + ((size_t)n * TV + m0) * C_;
#pragma unroll
    for (int j = 0; j < 6; j++) {
        int chunk = tid + j * 256;          // 1536 = 64 rows * 24 chunks
        int r = chunk / 24, c8 = chunk % 24;
        *(uint4*)&As[r * 200 + c8 * 8] = *(const uint4*)(ab + (size_t)r * C_ + c8 * 8);
    }
    if (tid < C_) {
        float inv = gamma[tid] * rsqrtf(rvar[tid] + 1e-5f);
        invS[tid] = inv;
        shiftS[tid] = beta[tid] - rmean[tid] * inv + bff[tid] * inv;
    }
    __syncthreads();   // As complete -> safe to read fragments

    int wave = tid >> 6, lane = tid & 63;
    int mb = (wave >> 1) * 32, obw = (wave & 1) * 32;
    int lrow = lane & 15, lk = lane >> 4;

    // hoist A-fragments to registers (48 VGPR), read ONCE
    bf16x8 afrag[2][6];
#pragma unroll
    for (int ks = 0; ks < 6; ks++)
#pragma unroll
        for (int mt = 0; mt < 2; mt++)
            afrag[mt][ks] = *(const bf16x8*)&As[(mb + mt * 16 + lrow) * 200 + ks * 32 + lk * 8];

    for (int oi = 0; oi < 3; oi++) {
        int o0 = oi * 64;
        __syncthreads();               // afrag reads / prev epilogue zT reads done
#pragma unroll
        for (int j = 0; j < 6; j++) {
            int chunk = tid + j * 256;          // 1536 = 64 rows * 24 uint4
            int r = chunk / 24, c8 = chunk % 24;
            *(uint4*)&Bs[r * 200 + c8 * 8] =
                *(const uint4*)(Wbf + (size_t)(o0 + r) * C_ + c8 * 8);
        }
        __syncthreads();

        f32x4 acc[2][2];
#pragma unroll
        for (int i = 0; i < 2; i++)
#pragma unroll
            for (int j = 0; j < 2; j++) acc[i][j] = (f32x4){0.f, 0.f, 0.f, 0.f};

#pragma unroll
        for (int ks = 0; ks < 6; ks++) {
            bf16x8 b[2];
#pragma unroll
            for (int ot = 0; ot < 2; ot++)
                b[ot] = *(const bf16x8*)&Bs[(obw + ot * 16 + lrow) * 200 + ks * 32 + lk * 8];
#pragma unroll
            for (int mt = 0; mt < 2; mt++)
#pragma unroll
                for (int ot = 0; ot < 2; ot++)
                    acc[mt][ot] = MFMA16(afrag[mt][ks], b[ot], acc[mt][ot]);
        }

        __syncthreads();               // all waves done reading Bs (W)
#pragma unroll
        for (int mt = 0; mt < 2; mt++)
#pragma unroll
            for (int ot = 0; ot < 2; ot++) {
                int o = obw + ot * 16 + lrow;
                float inv = invS[o0 + o], sh = shiftS[o0 + o];
#pragma unroll
                for (int r = 0; r < 4; r++) {
                    int m = mb + mt * 16 + lk * 4 + r;
                    zT[o * 68 + m] = acc[mt][ot][r] * inv + sh;
                }
            }
        __syncthreads();

        const float* xb = x + ((size_t)n * C_ + o0) * TV + m0;
        float* ob2 = out + ((size_t)n * C_ + o0) * TV + m0;
#pragma unroll
        for (int j = 0; j < 4; j++) {
            int chunk = tid + j * 256;          // 1024 = 64 rows * 16 f4
            int o = chunk >> 4, m4 = chunk & 15;
            float4 zv = *(float4*)&zT[o * 68 + m4 * 4];
            float4 xv = *(const float4*)(xb + (size_t)o * TV + m4 * 4);
            float4 res; float a;
            a = xv.x + zv.x; res.x = (a >= 0.f) ? a : 0.1f * a;
            a = xv.y + zv.y; res.y = (a >= 0.f) ? a : 0.1f * a;
            a = xv.z + zv.z; res.z = (a >= 0.f) ? a : 0.1f * a;
            a = xv.w + zv.w; res.w = (a >= 0.f) ? a : 0.1f * a;
            *(float4*)(ob2 + (size_t)o * TV + m4 * 4) = res;
        }
    }
}

// ---------------------------------------------------------------------------
extern "C" void kernel_launch(void* const* d_in, const int* in_sizes, int n_in,
                              void* d_out, int out_size, void* d_ws, size_t ws_size,
                              hipStream_t stream) {
    (void)in_sizes; (void)n_in; (void)out_size; (void)ws_size;
    const float* x    = (const float*)d_in[0];
    const float* Wqkv = (const float*)d_in[1];
    const float* bqkv = (const float*)d_in[2];
    const float* Wff  = (const float*)d_in[3];
    const float* bff  = (const float*)d_in[4];
    const float* gam  = (const float*)d_in[5];
    const float* bet  = (const float*)d_in[6];
    const float* rme  = (const float*)d_in[7];
    const float* rva  = (const float*)d_in[8];
    float* out = (float*)d_out;
    float* attOut = out + OUT_ELEMS;   // fp32 att segment of the output tuple

    char* ws = (char*)d_ws;
    ushort* qkvT = (ushort*)ws;                        // 235,929,600 B
    // partial (7.86 MB) and yT (78.6 MB) alias: partial is dead before k3 runs
    float*  partial = (float*)(ws + 235929600);
    ushort* yT      = (ushort*)(ws + 235929600);
    // WqkvB aliases the partial region: written by kconv, consumed by k1,
    // clobbered only later by k2_att's partial writes.
    ushort* WqkvB   = (ushort*)(ws + 235929600);
    // WffB aliases qkvT: qkvT is dead after k3 (k4 doesn't read it).
    ushort* WffB    = (ushort*)ws;

    kconv<<<dim3(108), 256, 0, stream>>>(Wqkv, WqkvB, 27648);   // 576*192/4
    k1_qkv<<<dim3(25, 64), 512, 0, stream>>>(x, WqkvB, bqkv, qkvT);
    k2_att<<<dim3(NCHUNK, 3, 64), 256, 0, stream>>>(qkvT, partial);
    k2_reduce<<<dim3(469), 256, 0, stream>>>(partial, attOut);
    k3_y<<<dim3(128, 64), 192, 0, stream>>>(qkvT, attOut, yT);
    kconv<<<dim3(36), 256, 0, stream>>>(Wff, WffB, 9216);       // 192*192/4
    k4_out<<<dim3(50, 64), 256, 0, stream>>>(yT, WffB, bff, gam, bet, rme, rva, x, out);
}